// Round 2
// baseline (16618.376 us; speedup 1.0000x reference)
//
#include <hip/hip_runtime.h>

#define EPSF 1e-8f

// ---------------------------------------------------------------------------
// Generic GVP layer, executed by ONE wave (64 lanes) on per-wave LDS buffers.
// All __syncthreads() are hit uniformly by every wave in the block.
//   vh  = wh @ v            [H,3]
//   vn  = ||vh||            [H]      (appended to S at S[SIcat..SIcat+H))
//   s_o = [s, vn] @ wsw^T+b [SO]     (+ relu if ACT)
//   v_o = wv @ vh           [VO,3]   (* sigmoid(||v_o||) if ACT)
// ---------------------------------------------------------------------------
template<int VI, int H, int SIcat, int SO, int VO, bool ACT>
__device__ __forceinline__ void gvp_layer(
    float* S, const float* V, float* VH, float* SOb, float* VOb,
    const float* __restrict__ wh, const float* __restrict__ wsw,
    const float* __restrict__ wsb, const float* __restrict__ wv, int lane)
{
    // vh
    for (int idx = lane; idx < H * 3; idx += 64) {
        int h = idx / 3, t = idx - h * 3;
        const float* w = wh + h * VI;
        float acc = 0.f;
        #pragma unroll
        for (int c = 0; c < VI; ++c) acc = fmaf(V[c * 3 + t], w[c], acc);
        VH[idx] = acc;
    }
    __syncthreads();
    // vn -> S[SIcat + h]
    for (int h = lane; h < H; h += 64) {
        float a = VH[h * 3 + 0], b = VH[h * 3 + 1], c = VH[h * 3 + 2];
        S[SIcat + h] = sqrtf(fmaxf(a * a + b * b + c * c, EPSF));
    }
    __syncthreads();
    // s_out
    constexpr int K = SIcat + H;
    for (int o = lane; o < SO; o += 64) {
        const float* w = wsw + (size_t)o * K;
        float acc = wsb[o];
        #pragma unroll 8
        for (int k = 0; k < K; ++k) acc = fmaf(S[k], w[k], acc);
        if (ACT) acc = fmaxf(acc, 0.f);
        SOb[o] = acc;
    }
    // v_out
    for (int idx = lane; idx < VO * 3; idx += 64) {
        int o = idx / 3, t = idx - o * 3;
        const float* w = wv + o * H;
        float acc = 0.f;
        #pragma unroll
        for (int h = 0; h < H; ++h) acc = fmaf(VH[h * 3 + t], w[h], acc);
        VOb[idx] = acc;
    }
    __syncthreads();
    if (ACT) {
        for (int o = lane; o < VO; o += 64) {
            float a = VOb[o * 3 + 0], b = VOb[o * 3 + 1], c = VOb[o * 3 + 2];
            float nrm = sqrtf(fmaxf(a * a + b * b + c * c, EPSF));
            float sg = 1.f / (1.f + __expf(-nrm));
            VOb[o * 3 + 0] = a * sg; VOb[o * 3 + 1] = b * sg; VOb[o * 3 + 2] = c * sg;
        }
        __syncthreads();
    }
}

// ---------------------------------------------------------------------------
// Edge kernel: 1 wave = 1 edge; 4 waves / block.
// gather(cat) -> m1 -> m2 -> m3 -> atomic scatter-add into fp32 workspace
// ---------------------------------------------------------------------------
struct EdgeScratch {
    float S[324];    // cat s-input (288) + vn (33) = 321
    float V[100];    // cat v-input (33*3 = 99)
    float VH[100];   // vh (33*3)
    float SO[128];
    float VO[48];
};

__global__ __launch_bounds__(256)
void edge_kernel(const float* __restrict__ s, const float* __restrict__ v,
                 const int* __restrict__ eidx,
                 const float* __restrict__ es, const float* __restrict__ ev,
                 const float* __restrict__ m1_wh, const float* __restrict__ m1_wsw,
                 const float* __restrict__ m1_wsb, const float* __restrict__ m1_wv,
                 const float* __restrict__ m2_wh, const float* __restrict__ m2_wsw,
                 const float* __restrict__ m2_wsb, const float* __restrict__ m2_wv,
                 const float* __restrict__ m3_wh, const float* __restrict__ m3_wsw,
                 const float* __restrict__ m3_wsb, const float* __restrict__ m3_wv,
                 float* __restrict__ agg_s, float* __restrict__ agg_v,
                 float* __restrict__ cnt, int E)
{
    __shared__ EdgeScratch wsB[4];
    const int wave = threadIdx.x >> 6, lane = threadIdx.x & 63;
    EdgeScratch& W = wsB[wave];

    const int e0 = blockIdx.x * 4 + wave;
    const bool writer = (e0 < E);
    const int e = writer ? e0 : (E - 1);
    const int src = eidx[e];
    const int dst = eidx[E + e];

    // gather: S = [s[src](128), edge_s(32), s[dst](128)]; V = [v[src], ev, v[dst]]
    if (lane < 32) {
        const float4 a = ((const float4*)(s + (size_t)src * 128))[lane];
        const float4 b = ((const float4*)(s + (size_t)dst * 128))[lane];
        ((float4*)(W.S))[lane]      = a;   // S[0..128)
        ((float4*)(W.S + 160))[lane] = b;  // S[160..288)
    }
    if (lane < 8)
        ((float4*)(W.S + 128))[lane] = ((const float4*)(es + (size_t)e * 32))[lane];
    if (lane < 12) {
        const float4 a = ((const float4*)(v + (size_t)src * 48))[lane];
        const float4 b = ((const float4*)(v + (size_t)dst * 48))[lane];
        ((float4*)(W.V))[lane] = a;        // V[0..48)
        W.V[51 + 4 * lane + 0] = b.x;      // V[51..99) (unaligned LDS dest)
        W.V[51 + 4 * lane + 1] = b.y;
        W.V[51 + 4 * lane + 2] = b.z;
        W.V[51 + 4 * lane + 3] = b.w;
    }
    if (lane < 3) W.V[48 + lane] = ev[(size_t)e * 3 + lane];
    __syncthreads();

    gvp_layer<33, 33, 288, 128, 16, true>(W.S, W.V, W.VH, W.SO, W.VO,
                                          m1_wh, m1_wsw, m1_wsb, m1_wv, lane);
    for (int i = lane; i < 128; i += 64) W.S[i] = W.SO[i];
    for (int i = lane; i < 48;  i += 64) W.V[i] = W.VO[i];
    __syncthreads();

    gvp_layer<16, 16, 128, 128, 16, true>(W.S, W.V, W.VH, W.SO, W.VO,
                                          m2_wh, m2_wsw, m2_wsb, m2_wv, lane);
    for (int i = lane; i < 128; i += 64) W.S[i] = W.SO[i];
    for (int i = lane; i < 48;  i += 64) W.V[i] = W.VO[i];
    __syncthreads();

    gvp_layer<16, 16, 128, 128, 16, false>(W.S, W.V, W.VH, W.SO, W.VO,
                                           m3_wh, m3_wsw, m3_wsb, m3_wv, lane);

    if (writer) {
        for (int i = lane; i < 128; i += 64) atomicAdd(&agg_s[(size_t)dst * 128 + i], W.SO[i]);
        for (int i = lane; i < 48;  i += 64) atomicAdd(&agg_v[(size_t)dst * 48 + i], W.VO[i]);
        if (lane == 0) atomicAdd(&cnt[dst], 1.0f);
    }
}

// ---------------------------------------------------------------------------
// LayerNorm (scalar LN over 128 + vector-channel norm over 16 chans), one wave.
// ---------------------------------------------------------------------------
__device__ __forceinline__ void layer_norm(float* S, float* V,
    const float* __restrict__ g, const float* __restrict__ b, float* red, int lane)
{
    float x0 = S[lane], x1 = S[lane + 64];
    float sum = x0 + x1;
    #pragma unroll
    for (int off = 32; off > 0; off >>= 1) sum += __shfl_xor(sum, off, 64);
    float mu = sum * (1.f / 128.f);
    float d0 = x0 - mu, d1 = x1 - mu;
    float vs = d0 * d0 + d1 * d1;
    #pragma unroll
    for (int off = 32; off > 0; off >>= 1) vs += __shfl_xor(vs, off, 64);
    float rstd = rsqrtf(vs * (1.f / 128.f) + 1e-5f);
    S[lane]      = d0 * rstd * g[lane]      + b[lane];
    S[lane + 64] = d1 * rstd * g[lane + 64] + b[lane + 64];

    if (lane < 16) {
        float a = V[lane * 3], bb = V[lane * 3 + 1], cc = V[lane * 3 + 2];
        float vn = fmaxf(a * a + bb * bb + cc * cc, EPSF);
        red[lane]      = vn;
        red[16 + lane] = (vn > 2.f * EPSF) ? 1.f : 0.f;
    }
    __syncthreads();
    float sn = 0.f, sm = 0.f;
    #pragma unroll
    for (int i = 0; i < 16; ++i) { sn += red[i] * red[16 + i]; sm += red[16 + i]; }
    float rvm = rsqrtf(sn / (EPSF + sm) + EPSF);
    for (int j = lane; j < 48; j += 64) V[j] = red[16 + j / 3] * V[j] * rvm;
    __syncthreads();
}

// ---------------------------------------------------------------------------
// Node kernel: 1 wave = 1 node; residual + LN0 + f1 + f2 + residual + LN1
// ---------------------------------------------------------------------------
struct NodeScratch {
    float S1[128];   // post-LN0 scalar (saved for residual)
    float V1[48];    // post-LN0 vector
    float CAT[160];  // f1 input cat [s1(128), vn(32)]
    float FS[548];   // f1 s-out (512) + f2 vn (32)
    float FV[96];    // f1 v-out (32*3)
    float VH[96];    // vh scratch (32*3)
    float OS[128];
    float OV[48];
    float red[32];
};

__global__ __launch_bounds__(256)
void node_kernel(const float* __restrict__ s, const float* __restrict__ v,
                 const float* __restrict__ f1_wh, const float* __restrict__ f1_wsw,
                 const float* __restrict__ f1_wsb, const float* __restrict__ f1_wv,
                 const float* __restrict__ f2_wh, const float* __restrict__ f2_wsw,
                 const float* __restrict__ f2_wsb, const float* __restrict__ f2_wv,
                 const float* __restrict__ ln0_g, const float* __restrict__ ln0_b,
                 const float* __restrict__ ln1_g, const float* __restrict__ ln1_b,
                 const float* __restrict__ agg_s, const float* __restrict__ agg_v,
                 const float* __restrict__ cnt,
                 float* __restrict__ out, int N)
{
    __shared__ NodeScratch wsB[4];
    const int wave = threadIdx.x >> 6, lane = threadIdx.x & 63;
    NodeScratch& W = wsB[wave];

    const int n0 = blockIdx.x * 4 + wave;
    const bool writer = (n0 < N);
    const int n = writer ? n0 : (N - 1);

    const float inv = 1.f / fmaxf(cnt[n], 1.f);
    if (lane < 32) {
        const float4 a = ((const float4*)(s + (size_t)n * 128))[lane];
        const float4 b = ((const float4*)(agg_s + (size_t)n * 128))[lane];
        float4 r;
        r.x = a.x + b.x * inv; r.y = a.y + b.y * inv;
        r.z = a.z + b.z * inv; r.w = a.w + b.w * inv;
        ((float4*)(W.S1))[lane] = r;
    }
    if (lane < 12) {
        const float4 a = ((const float4*)(v + (size_t)n * 48))[lane];
        const float4 b = ((const float4*)(agg_v + (size_t)n * 48))[lane];
        float4 r;
        r.x = a.x + b.x * inv; r.y = a.y + b.y * inv;
        r.z = a.z + b.z * inv; r.w = a.w + b.w * inv;
        ((float4*)(W.V1))[lane] = r;
    }
    __syncthreads();

    layer_norm(W.S1, W.V1, ln0_g, ln0_b, W.red, lane);

    for (int i = lane; i < 128; i += 64) W.CAT[i] = W.S1[i];
    __syncthreads();

    gvp_layer<16, 32, 128, 512, 32, true>(W.CAT, W.V1, W.VH, W.FS, W.FV,
                                          f1_wh, f1_wsw, f1_wsb, f1_wv, lane);
    gvp_layer<32, 32, 512, 128, 16, false>(W.FS, W.FV, W.VH, W.OS, W.OV,
                                           f2_wh, f2_wsw, f2_wsb, f2_wv, lane);

    for (int i = lane; i < 128; i += 64) W.OS[i] += W.S1[i];
    for (int i = lane; i < 48;  i += 64) W.OV[i] += W.V1[i];
    __syncthreads();

    layer_norm(W.OS, W.OV, ln1_g, ln1_b, W.red, lane);

    if (writer) {
        if (lane < 32)
            ((float4*)(out + (size_t)n * 128))[lane] = ((const float4*)(W.OS))[lane];
        if (lane < 12)
            ((float4*)(out + (size_t)N * 128 + (size_t)n * 48))[lane] = ((const float4*)(W.OV))[lane];
    }
}

// ---------------------------------------------------------------------------
extern "C" void kernel_launch(void* const* d_in, const int* in_sizes, int n_in,
                              void* d_out, int out_size, void* d_ws, size_t ws_size,
                              hipStream_t stream)
{
    const float* s    = (const float*)d_in[0];
    const float* v    = (const float*)d_in[1];
    const int*   eidx = (const int*)d_in[2];
    const float* es   = (const float*)d_in[3];
    const float* ev   = (const float*)d_in[4];
    const float* m1_wh = (const float*)d_in[5];
    const float* m1_wsw = (const float*)d_in[6];
    const float* m1_wsb = (const float*)d_in[7];
    const float* m1_wv = (const float*)d_in[8];
    const float* m2_wh = (const float*)d_in[9];
    const float* m2_wsw = (const float*)d_in[10];
    const float* m2_wsb = (const float*)d_in[11];
    const float* m2_wv = (const float*)d_in[12];
    const float* m3_wh = (const float*)d_in[13];
    const float* m3_wsw = (const float*)d_in[14];
    const float* m3_wsb = (const float*)d_in[15];
    const float* m3_wv = (const float*)d_in[16];
    const float* f1_wh = (const float*)d_in[17];
    const float* f1_wsw = (const float*)d_in[18];
    const float* f1_wsb = (const float*)d_in[19];
    const float* f1_wv = (const float*)d_in[20];
    const float* f2_wh = (const float*)d_in[21];
    const float* f2_wsw = (const float*)d_in[22];
    const float* f2_wsb = (const float*)d_in[23];
    const float* f2_wv = (const float*)d_in[24];
    const float* ln0_g = (const float*)d_in[25];
    const float* ln0_b = (const float*)d_in[26];
    const float* ln1_g = (const float*)d_in[27];
    const float* ln1_b = (const float*)d_in[28];

    const int N = in_sizes[0] / 128;
    const int E = in_sizes[2] / 2;

    float* agg_s = (float*)d_ws;                       // N*128 fp32
    float* agg_v = agg_s + (size_t)N * 128;            // N*48  fp32
    float* cnt   = agg_v + (size_t)N * 48;             // N     fp32

    hipMemsetAsync(d_ws, 0, (size_t)N * 177 * sizeof(float), stream);

    edge_kernel<<<dim3((E + 3) / 4), dim3(256), 0, stream>>>(
        s, v, eidx, es, ev,
        m1_wh, m1_wsw, m1_wsb, m1_wv,
        m2_wh, m2_wsw, m2_wsb, m2_wv,
        m3_wh, m3_wsw, m3_wsb, m3_wv,
        agg_s, agg_v, cnt, E);

    node_kernel<<<dim3((N + 3) / 4), dim3(256), 0, stream>>>(
        s, v,
        f1_wh, f1_wsw, f1_wsb, f1_wv,
        f2_wh, f2_wsw, f2_wsb, f2_wv,
        ln0_g, ln0_b, ln1_g, ln1_b,
        agg_s, agg_v, cnt,
        (float*)d_out, N);
}

// Round 3
// 3820.444 us; speedup vs baseline: 4.3499x; 4.3499x over previous
//
#include <hip/hip_runtime.h>

#define EPSF 1e-8f
constexpr int ED = 4;   // edges (or nodes) per wave

// ---------------------------------------------------------------------------
// GVP layer for ONE wave processing ED=4 items on strided per-wave LDS buffers.
// Weight loads are float4 and amortized across the 4 items; activation (S)
// reads are float4 LDS broadcasts shared across OF output rows per lane.
//   vh  = wh @ v       [H,3];  vn = ||vh|| -> S[SIcat..SIcat+H)
//   s_o = S[0..KP) @ wswP^T + b   (wswP row-stride KP, zero-padded)
//   v_o = wv @ vh      [VO,3]
// ---------------------------------------------------------------------------
template<int VI, int H, int SIcat, int KP, int SO, int VO, bool ACT,
         int SSTR, int VSTR, int HSTR, int SOSTR, int VOSTR>
__device__ __forceinline__ void gvp4(
    float* S, const float* V, float* VH, float* SOb, float* VOb,
    const float* __restrict__ wh, const float* __restrict__ wswP,
    const float* __restrict__ wsb, const float* __restrict__ wv, int lane)
{
    static_assert(SO % 64 == 0 && KP % 4 == 0, "shape");
    // vh = wh @ v
    for (int idx = lane; idx < H * 3; idx += 64) {
        const int h = idx / 3, t = idx - h * 3;
        const float* w = wh + h * VI;
        float acc[ED] = {0.f, 0.f, 0.f, 0.f};
        for (int c = 0; c < VI; ++c) {
            const float wc = w[c];
            #pragma unroll
            for (int e = 0; e < ED; ++e) acc[e] = fmaf(V[e * VSTR + c * 3 + t], wc, acc[e]);
        }
        #pragma unroll
        for (int e = 0; e < ED; ++e) VH[e * HSTR + idx] = acc[e];
    }
    __syncthreads();
    // vn -> S tail
    for (int h = lane; h < H; h += 64) {
        #pragma unroll
        for (int e = 0; e < ED; ++e) {
            const float a = VH[e * HSTR + h * 3 + 0], b = VH[e * HSTR + h * 3 + 1],
                        c = VH[e * HSTR + h * 3 + 2];
            S[e * SSTR + SIcat + h] = sqrtf(fmaxf(a * a + b * b + c * c, EPSF));
        }
    }
    __syncthreads();
    // s_out: OF output rows per lane, ED items, float4 K-steps
    constexpr int OF = SO / 64;
    {
        float acc[OF][ED];
        #pragma unroll
        for (int of = 0; of < OF; ++of) {
            const float bias = wsb[lane + of * 64];
            #pragma unroll
            for (int e = 0; e < ED; ++e) acc[of][e] = bias;
        }
        for (int k = 0; k < KP; k += 4) {
            float4 sv[ED];
            #pragma unroll
            for (int e = 0; e < ED; ++e) sv[e] = *(const float4*)&S[e * SSTR + k];
            #pragma unroll
            for (int of = 0; of < OF; ++of) {
                const float4 w = *(const float4*)&wswP[(size_t)(lane + of * 64) * KP + k];
                #pragma unroll
                for (int e = 0; e < ED; ++e) {
                    acc[of][e] = fmaf(w.x, sv[e].x, acc[of][e]);
                    acc[of][e] = fmaf(w.y, sv[e].y, acc[of][e]);
                    acc[of][e] = fmaf(w.z, sv[e].z, acc[of][e]);
                    acc[of][e] = fmaf(w.w, sv[e].w, acc[of][e]);
                }
            }
        }
        #pragma unroll
        for (int of = 0; of < OF; ++of)
            #pragma unroll
            for (int e = 0; e < ED; ++e) {
                float a = acc[of][e];
                if (ACT) a = fmaxf(a, 0.f);
                SOb[e * SOSTR + lane + of * 64] = a;
            }
    }
    // v_out = wv @ vh
    for (int idx = lane; idx < VO * 3; idx += 64) {
        const int o = idx / 3, t = idx - o * 3;
        const float* w = wv + o * H;
        float acc[ED] = {0.f, 0.f, 0.f, 0.f};
        for (int h = 0; h < H; ++h) {
            const float wc = w[h];
            #pragma unroll
            for (int e = 0; e < ED; ++e) acc[e] = fmaf(VH[e * HSTR + h * 3 + t], wc, acc[e]);
        }
        #pragma unroll
        for (int e = 0; e < ED; ++e) VOb[e * VOSTR + idx] = acc[e];
    }
    __syncthreads();
    if (ACT) {
        for (int o = lane; o < VO; o += 64) {
            #pragma unroll
            for (int e = 0; e < ED; ++e) {
                float* p = VOb + e * VOSTR + o * 3;
                const float a = p[0], b = p[1], c = p[2];
                const float nrm = sqrtf(fmaxf(a * a + b * b + c * c, EPSF));
                const float sg = 1.f / (1.f + __expf(-nrm));
                p[0] = a * sg; p[1] = b * sg; p[2] = c * sg;
            }
        }
        __syncthreads();
    }
}

// ---------------------------------------------------------------------------
// Pack m1_wsw [128,321] -> [128,324] zero-padded so rows are 16B-aligned.
// ---------------------------------------------------------------------------
__global__ void pack_m1(const float* __restrict__ w, float* __restrict__ out) {
    const int i = blockIdx.x * 256 + threadIdx.x;
    if (i >= 128 * 324) return;
    const int o = i / 324, k = i - o * 324;
    out[i] = (k < 321) ? w[o * 321 + k] : 0.f;
}

// ---------------------------------------------------------------------------
// Edge kernel: 1 wave = 4 edges; 4 waves/block (16 edges).
// Per-wave LDS layout (floats): S 4x324 @0 | V 4x100 @1296 | VH 4x100 @1696 |
//                               SO 4x128 @2096 | VO 4x48 @2608 | total 2800
// ---------------------------------------------------------------------------
__global__ __launch_bounds__(256)
void edge_kernel(const float* __restrict__ s, const float* __restrict__ v,
                 const int* __restrict__ eidx,
                 const float* __restrict__ es, const float* __restrict__ ev,
                 const float* __restrict__ m1_wh, const float* __restrict__ m1_wswP,
                 const float* __restrict__ m1_wsb, const float* __restrict__ m1_wv,
                 const float* __restrict__ m2_wh, const float* __restrict__ m2_wsw,
                 const float* __restrict__ m2_wsb, const float* __restrict__ m2_wv,
                 const float* __restrict__ m3_wh, const float* __restrict__ m3_wsw,
                 const float* __restrict__ m3_wsb, const float* __restrict__ m3_wv,
                 float* __restrict__ agg_s, float* __restrict__ agg_v,
                 float* __restrict__ cnt, int E)
{
    __shared__ __align__(16) float esm[4 * 2800];
    const int wave = threadIdx.x >> 6, lane = threadIdx.x & 63;
    float* Sb  = esm + wave * 2800;
    float* Vb  = Sb + 1296;
    float* VHb = Sb + 1696;
    float* SOb = Sb + 2096;
    float* VOb = Sb + 2608;

    const int e0 = (blockIdx.x * 4 + wave) * ED;
    int dsts[ED];
    bool oks[ED];

    #pragma unroll
    for (int e = 0; e < ED; ++e) {
        const int eg = e0 + e;
        oks[e] = (eg < E);
        const int ee = oks[e] ? eg : (E - 1);
        const int src = eidx[ee];
        dsts[e] = eidx[E + ee];
        float* S = Sb + e * 324;
        float* V = Vb + e * 100;
        if (lane < 32) {
            const float4 a = ((const float4*)(s + (size_t)src * 128))[lane];
            const float4 b = ((const float4*)(s + (size_t)dsts[e] * 128))[lane];
            ((float4*)S)[lane] = a;
            ((float4*)(S + 160))[lane] = b;
        }
        if (lane < 8)
            ((float4*)(S + 128))[lane] = ((const float4*)(es + (size_t)ee * 32))[lane];
        if (lane < 12) {
            const float4 a = ((const float4*)(v + (size_t)src * 48))[lane];
            const float4 b = ((const float4*)(v + (size_t)dsts[e] * 48))[lane];
            ((float4*)V)[lane] = a;
            V[51 + 4 * lane + 0] = b.x; V[51 + 4 * lane + 1] = b.y;
            V[51 + 4 * lane + 2] = b.z; V[51 + 4 * lane + 3] = b.w;
        }
        if (lane < 3) {
            V[48 + lane] = ev[(size_t)ee * 3 + lane];
            S[321 + lane] = 0.f;     // K-pad for m1
        }
    }
    __syncthreads();

    gvp4<33, 33, 288, 324, 128, 16, true, 324, 100, 100, 128, 48>(
        Sb, Vb, VHb, SOb, VOb, m1_wh, m1_wswP, m1_wsb, m1_wv, lane);
    #pragma unroll
    for (int e = 0; e < ED; ++e) {
        for (int i = lane; i < 128; i += 64) Sb[e * 324 + i] = SOb[e * 128 + i];
        if (lane < 48) Vb[e * 100 + lane] = VOb[e * 48 + lane];
    }
    __syncthreads();

    gvp4<16, 16, 128, 144, 128, 16, true, 324, 100, 100, 128, 48>(
        Sb, Vb, VHb, SOb, VOb, m2_wh, m2_wsw, m2_wsb, m2_wv, lane);
    #pragma unroll
    for (int e = 0; e < ED; ++e) {
        for (int i = lane; i < 128; i += 64) Sb[e * 324 + i] = SOb[e * 128 + i];
        if (lane < 48) Vb[e * 100 + lane] = VOb[e * 48 + lane];
    }
    __syncthreads();

    gvp4<16, 16, 128, 144, 128, 16, false, 324, 100, 100, 128, 48>(
        Sb, Vb, VHb, SOb, VOb, m3_wh, m3_wsw, m3_wsb, m3_wv, lane);

    #pragma unroll
    for (int e = 0; e < ED; ++e) {
        if (!oks[e]) continue;
        const int dst = dsts[e];
        for (int i = lane; i < 128; i += 64)
            atomicAdd(&agg_s[(size_t)dst * 128 + i], SOb[e * 128 + i]);
        if (lane < 48)
            atomicAdd(&agg_v[(size_t)dst * 48 + lane], VOb[e * 48 + lane]);
        if (lane == 0) atomicAdd(&cnt[dst], 1.0f);
    }
}

// ---------------------------------------------------------------------------
// LayerNorm for ED items (scalar LN over 128 + vector-channel norm, 16 chans)
// ---------------------------------------------------------------------------
template<int SSTR, int VSTR>
__device__ __forceinline__ void layer_norm4(float* S, float* V,
    const float* __restrict__ g, const float* __restrict__ b, float* red, int lane)
{
    #pragma unroll
    for (int e = 0; e < ED; ++e) {
        float x0 = S[e * SSTR + lane], x1 = S[e * SSTR + 64 + lane];
        float sum = x0 + x1;
        #pragma unroll
        for (int off = 32; off > 0; off >>= 1) sum += __shfl_xor(sum, off, 64);
        const float mu = sum * (1.f / 128.f);
        const float d0 = x0 - mu, d1 = x1 - mu;
        float vs = d0 * d0 + d1 * d1;
        #pragma unroll
        for (int off = 32; off > 0; off >>= 1) vs += __shfl_xor(vs, off, 64);
        const float rstd = rsqrtf(vs * (1.f / 128.f) + 1e-5f);
        S[e * SSTR + lane]      = d0 * rstd * g[lane]      + b[lane];
        S[e * SSTR + 64 + lane] = d1 * rstd * g[lane + 64] + b[lane + 64];

        if (lane < 16) {
            const float a = V[e * VSTR + lane * 3], bb = V[e * VSTR + lane * 3 + 1],
                        cc = V[e * VSTR + lane * 3 + 2];
            const float vn = fmaxf(a * a + bb * bb + cc * cc, EPSF);
            red[lane]      = vn;
            red[16 + lane] = (vn > 2.f * EPSF) ? 1.f : 0.f;
        }
        __syncthreads();
        float sn = 0.f, sm = 0.f;
        #pragma unroll
        for (int i = 0; i < 16; ++i) { sn += red[i] * red[16 + i]; sm += red[16 + i]; }
        const float rvm = rsqrtf(sn / (EPSF + sm) + EPSF);
        if (lane < 48) V[e * VSTR + lane] = red[16 + lane / 3] * V[e * VSTR + lane] * rvm;
        __syncthreads();
    }
}

// ---------------------------------------------------------------------------
// Node kernel: 1 wave = 4 nodes; 2 waves/block (8 nodes), 128 threads.
// Per-wave LDS (floats): S1 4x160 @0 | V1 4x48 @640 | FS 4x544 @832 |
//   FV 4x96 @3008 | VH 4x96 @3392 | OS 4x128 @3776 | OV 4x48 @4288 |
//   red 32 @4480 | total 4608
// ---------------------------------------------------------------------------
__global__ __launch_bounds__(128)
void node_kernel(const float* __restrict__ s, const float* __restrict__ v,
                 const float* __restrict__ f1_wh, const float* __restrict__ f1_wsw,
                 const float* __restrict__ f1_wsb, const float* __restrict__ f1_wv,
                 const float* __restrict__ f2_wh, const float* __restrict__ f2_wsw,
                 const float* __restrict__ f2_wsb, const float* __restrict__ f2_wv,
                 const float* __restrict__ ln0_g, const float* __restrict__ ln0_b,
                 const float* __restrict__ ln1_g, const float* __restrict__ ln1_b,
                 const float* __restrict__ agg_s, const float* __restrict__ agg_v,
                 const float* __restrict__ cnt,
                 float* __restrict__ out, int N)
{
    __shared__ __align__(16) float nsm[2 * 4608];
    const int wave = threadIdx.x >> 6, lane = threadIdx.x & 63;
    float* S1  = nsm + wave * 4608;
    float* V1  = S1 + 640;
    float* FS  = S1 + 832;
    float* FV  = S1 + 3008;
    float* VHb = S1 + 3392;
    float* OS  = S1 + 3776;
    float* OV  = S1 + 4288;
    float* red = S1 + 4480;

    const int n0 = (blockIdx.x * 2 + wave) * ED;
    bool oks[ED];
    #pragma unroll
    for (int e = 0; e < ED; ++e) {
        const int ng = n0 + e;
        oks[e] = (ng < N);
        const int n = oks[e] ? ng : (N - 1);
        const float inv = 1.f / fmaxf(cnt[n], 1.f);
        if (lane < 32) {
            const float4 a = ((const float4*)(s + (size_t)n * 128))[lane];
            const float4 b = ((const float4*)(agg_s + (size_t)n * 128))[lane];
            float4 r; r.x = a.x + b.x * inv; r.y = a.y + b.y * inv;
            r.z = a.z + b.z * inv; r.w = a.w + b.w * inv;
            ((float4*)(S1 + e * 160))[lane] = r;
        }
        if (lane < 12) {
            const float4 a = ((const float4*)(v + (size_t)n * 48))[lane];
            const float4 b = ((const float4*)(agg_v + (size_t)n * 48))[lane];
            float4 r; r.x = a.x + b.x * inv; r.y = a.y + b.y * inv;
            r.z = a.z + b.z * inv; r.w = a.w + b.w * inv;
            ((float4*)(V1 + e * 48))[lane] = r;
        }
    }
    __syncthreads();

    layer_norm4<160, 48>(S1, V1, ln0_g, ln0_b, red, lane);

    // f1: reads S1[0..128) (+vn at 128..160), writes FS/FV
    gvp4<16, 32, 128, 160, 512, 32, true, 160, 48, 96, 544, 96>(
        S1, V1, VHb, FS, FV, f1_wh, f1_wsw, f1_wsb, f1_wv, lane);
    // f2: reads FS[0..512) (+vn at 512..544), writes OS/OV
    gvp4<32, 32, 512, 544, 128, 16, false, 544, 96, 96, 128, 48>(
        FS, FV, VHb, OS, OV, f2_wh, f2_wsw, f2_wsb, f2_wv, lane);

    #pragma unroll
    for (int e = 0; e < ED; ++e) {
        for (int i = lane; i < 128; i += 64) OS[e * 128 + i] += S1[e * 160 + i];
        if (lane < 48) OV[e * 48 + lane] += V1[e * 48 + lane];
    }
    __syncthreads();

    layer_norm4<128, 48>(OS, OV, ln1_g, ln1_b, red, lane);

    #pragma unroll
    for (int e = 0; e < ED; ++e) {
        if (!oks[e]) continue;
        const int n = n0 + e;
        if (lane < 32)
            ((float4*)(out + (size_t)n * 128))[lane] = ((const float4*)(OS + e * 128))[lane];
        if (lane < 12)
            ((float4*)(out + (size_t)N * 128 + (size_t)n * 48))[lane] =
                ((const float4*)(OV + e * 48))[lane];
    }
}

// ---------------------------------------------------------------------------
extern "C" void kernel_launch(void* const* d_in, const int* in_sizes, int n_in,
                              void* d_out, int out_size, void* d_ws, size_t ws_size,
                              hipStream_t stream)
{
    const float* s    = (const float*)d_in[0];
    const float* v    = (const float*)d_in[1];
    const int*   eidx = (const int*)d_in[2];
    const float* es   = (const float*)d_in[3];
    const float* ev   = (const float*)d_in[4];
    const float* m1_wh = (const float*)d_in[5];
    const float* m1_wsw = (const float*)d_in[6];
    const float* m1_wsb = (const float*)d_in[7];
    const float* m1_wv = (const float*)d_in[8];
    const float* m2_wh = (const float*)d_in[9];
    const float* m2_wsw = (const float*)d_in[10];
    const float* m2_wsb = (const float*)d_in[11];
    const float* m2_wv = (const float*)d_in[12];
    const float* m3_wh = (const float*)d_in[13];
    const float* m3_wsw = (const float*)d_in[14];
    const float* m3_wsb = (const float*)d_in[15];
    const float* m3_wv = (const float*)d_in[16];
    const float* f1_wh = (const float*)d_in[17];
    const float* f1_wsw = (const float*)d_in[18];
    const float* f1_wsb = (const float*)d_in[19];
    const float* f1_wv = (const float*)d_in[20];
    const float* f2_wh = (const float*)d_in[21];
    const float* f2_wsw = (const float*)d_in[22];
    const float* f2_wsb = (const float*)d_in[23];
    const float* f2_wv = (const float*)d_in[24];
    const float* ln0_g = (const float*)d_in[25];
    const float* ln0_b = (const float*)d_in[26];
    const float* ln1_g = (const float*)d_in[27];
    const float* ln1_b = (const float*)d_in[28];

    const int N = in_sizes[0] / 128;
    const int E = in_sizes[2] / 2;

    float* agg_s = (float*)d_ws;                       // N*128 fp32
    float* agg_v = agg_s + (size_t)N * 128;            // N*48  fp32
    float* cnt   = agg_v + (size_t)N * 48;             // N     fp32
    float* m1p   = cnt + N;                            // 128*324 packed m1_wsw

    hipMemsetAsync(d_ws, 0, (size_t)N * 177 * sizeof(float), stream);
    pack_m1<<<dim3((128 * 324 + 255) / 256), dim3(256), 0, stream>>>(m1_wsw, m1p);

    edge_kernel<<<dim3((E + 15) / 16), dim3(256), 0, stream>>>(
        s, v, eidx, es, ev,
        m1_wh, m1p, m1_wsb, m1_wv,
        m2_wh, m2_wsw, m2_wsb, m2_wv,
        m3_wh, m3_wsw, m3_wsb, m3_wv,
        agg_s, agg_v, cnt, E);

    node_kernel<<<dim3((N + 7) / 8), dim3(128), 0, stream>>>(
        s, v,
        f1_wh, f1_wsw, f1_wsb, f1_wv,
        f2_wh, f2_wsw, f2_wsb, f2_wv,
        ln0_g, ln0_b, ln1_g, ln1_b,
        agg_s, agg_v, cnt,
        (float*)d_out, N);
}

// Round 5
// 2044.291 us; speedup vs baseline: 8.1292x; 1.8688x over previous
//
#include <hip/hip_runtime.h>

#define EPSF 1e-8f
constexpr int ED = 4;   // nodes per wave in node kernel

typedef __attribute__((ext_vector_type(8))) short short8;
typedef __attribute__((ext_vector_type(4))) float float4v;

// ---- fp32 -> bf16 hi/lo split (RNE) ---------------------------------------
__device__ __forceinline__ unsigned bfhi_bits(float x) {
    unsigned u = __float_as_uint(x);
    return (u + 0x7fffu + ((u >> 16) & 1u)) >> 16;
}
__device__ __forceinline__ float bits2f(unsigned b) { return __uint_as_float(b << 16); }
__device__ __forceinline__ void split_bf(float x, unsigned short& h, unsigned short& l) {
    unsigned hb = bfhi_bits(x);
    h = (unsigned short)hb;
    l = (unsigned short)bfhi_bits(x - bits2f(hb));
}

// ---------------------------------------------------------------------------
// Pack W[NO][K] fp32 (row-major) into MFMA B-fragment order, bf16 hi/lo.
// ---------------------------------------------------------------------------
__global__ void pack_w(const float* __restrict__ W, unsigned short* __restrict__ hi,
                       unsigned short* __restrict__ lo, int NO, int K, int steps) {
    const int gid = blockIdx.x * 256 + threadIdx.x;
    const int total = (NO >> 4) * steps * 512;
    if (gid >= total) return;
    const int j = gid & 7, l = (gid >> 3) & 63, rest = gid >> 9;
    const int t = rest % steps, nt = rest / steps;
    const int n = nt * 16 + (l & 15);
    const int k = t * 32 + ((l >> 4) << 3) + j;
    const float x = (k < K) ? W[(size_t)n * K + k] : 0.f;
    unsigned short h, lw;
    split_bf(x, h, lw);
    hi[gid] = h; lo[gid] = lw;
}

// ---------------------------------------------------------------------------
// 3-pass split-bf16 MFMA K-loop (validated by R4 s-output).
// ---------------------------------------------------------------------------
template<int STEPS, int NTPW, int ASTR>
__device__ __forceinline__ void kloop(const unsigned short* PAh, const unsigned short* PAl,
    const unsigned short* __restrict__ wph, const unsigned short* __restrict__ wpl,
    float4v* acc, int lane, int wave)
{
    const int m = lane & 15, q = lane >> 4;
    for (int t = 0; t < STEPS; ++t) {
        const int k0 = t * 32 + q * 8;
        const short8 ah = *(const short8*)(PAh + m * ASTR + k0);
        const short8 al = *(const short8*)(PAl + m * ASTR + k0);
        #pragma unroll
        for (int i = 0; i < NTPW; ++i) {
            const int nt = wave * NTPW + i;
            const size_t off = ((size_t)(nt * STEPS + t) * 64 + lane) * 8;
            const short8 bh = *(const short8*)(wph + off);
            const short8 bl = *(const short8*)(wpl + off);
            acc[i] = __builtin_amdgcn_mfma_f32_16x16x32_bf16(ah, bh, acc[i], 0, 0, 0);
            acc[i] = __builtin_amdgcn_mfma_f32_16x16x32_bf16(al, bh, acc[i], 0, 0, 0);
            acc[i] = __builtin_amdgcn_mfma_f32_16x16x32_bf16(ah, bl, acc[i], 0, 0, 0);
        }
    }
}

// ---------------------------------------------------------------------------
// Edge kernel: 16 edges per block, 256 threads (4 waves).  (R4 verbatim)
// ---------------------------------------------------------------------------
__global__ __launch_bounds__(256)
void edge_kernel(const float* __restrict__ s, const float* __restrict__ v,
                 const int* __restrict__ eidx,
                 const float* __restrict__ es, const float* __restrict__ ev,
                 const float* __restrict__ m1_wh, const float* __restrict__ m1_wsb,
                 const float* __restrict__ m1_wv,
                 const float* __restrict__ m2_wh, const float* __restrict__ m2_wsb,
                 const float* __restrict__ m2_wv,
                 const float* __restrict__ m3_wh, const float* __restrict__ m3_wsb,
                 const float* __restrict__ m3_wv,
                 const unsigned short* __restrict__ p1h, const unsigned short* __restrict__ p1l,
                 const unsigned short* __restrict__ p2h, const unsigned short* __restrict__ p2l,
                 const unsigned short* __restrict__ p3h, const unsigned short* __restrict__ p3l,
                 float* __restrict__ agg_s, float* __restrict__ agg_v,
                 float* __restrict__ cnt, int E)
{
    __shared__ __align__(16) unsigned short PAh[16 * 360], PAl[16 * 360];
    __shared__ __align__(16) unsigned short PBh[16 * 168], PBl[16 * 168];
    __shared__ float B0[16 * 101];
    __shared__ float B1[16 * 101];
    __shared__ float B2[16 * 51];
    __shared__ int ssrc[16], sgd[16], sdst[16], seid[16];

    const int tid = threadIdx.x, lane = tid & 63, wave = tid >> 6;
    const int e0 = blockIdx.x * 16;

    if (tid < 16) {
        const int eg = e0 + tid;
        const bool ok = (eg < E);
        const int ee = ok ? eg : (E - 1);
        seid[tid] = ee;
        ssrc[tid] = eidx[ee];
        const int d = eidx[E + ee];
        sgd[tid] = d;
        sdst[tid] = ok ? d : -1;
    }
    __syncthreads();

    for (int g = tid; g < 16 * 72; g += 256) {
        const int e = g / 72, c = g % 72;
        const float* srcp;
        int col;
        if (c < 32)      { srcp = s  + (size_t)ssrc[e] * 128 + 4 * c;        col = 4 * c; }
        else if (c < 40) { srcp = es + (size_t)seid[e] * 32 + 4 * (c - 32);  col = 128 + 4 * (c - 32); }
        else             { srcp = s  + (size_t)sgd[e]  * 128 + 4 * (c - 40); col = 160 + 4 * (c - 40); }
        const float4 x = *(const float4*)srcp;
        unsigned short h, l;
        split_bf(x.x, h, l); PAh[e*360+col+0] = h; PAl[e*360+col+0] = l;
        split_bf(x.y, h, l); PAh[e*360+col+1] = h; PAl[e*360+col+1] = l;
        split_bf(x.z, h, l); PAh[e*360+col+2] = h; PAl[e*360+col+2] = l;
        split_bf(x.w, h, l); PAh[e*360+col+3] = h; PAl[e*360+col+3] = l;
    }
    for (int g = tid; g < 16 * 25; g += 256) {
        const int e = g / 25, c = g % 25;
        if (c < 12) {
            const float4 x = *(const float4*)(v + (size_t)ssrc[e] * 48 + 4 * c);
            float* p = B0 + e * 101 + 4 * c;
            p[0] = x.x; p[1] = x.y; p[2] = x.z; p[3] = x.w;
        } else if (c == 12) {
            const float* q = ev + (size_t)seid[e] * 3;
            float* p = B0 + e * 101 + 48;
            p[0] = q[0]; p[1] = q[1]; p[2] = q[2];
        } else {
            const float4 x = *(const float4*)(v + (size_t)sgd[e] * 48 + 4 * (c - 13));
            float* p = B0 + e * 101 + 51 + 4 * (c - 13);
            p[0] = x.x; p[1] = x.y; p[2] = x.z; p[3] = x.w;
        }
    }
    for (int g = tid; g < 16 * 31; g += 256) {
        const int e = g / 31, c = 321 + g % 31;
        PAh[e*360+c] = 0; PAl[e*360+c] = 0;
    }
    __syncthreads();

    for (int g = tid; g < 16 * 99; g += 256) {
        const int e = g & 15, r = g >> 4, t = r % 3, h = r / 3;
        float a = 0.f;
        for (int c = 0; c < 33; ++c) a = fmaf(B0[e*101 + c*3 + t], m1_wh[h*33 + c], a);
        B1[e*101 + h*3 + t] = a;
    }
    __syncthreads();
    for (int g = tid; g < 16 * 33; g += 256) {
        const int e = g & 15, h = g >> 4;
        const float a = B1[e*101+h*3], b = B1[e*101+h*3+1], c = B1[e*101+h*3+2];
        const float vn = sqrtf(fmaxf(a*a + b*b + c*c, EPSF));
        unsigned short hh, ll; split_bf(vn, hh, ll);
        PAh[e*360 + 288 + h] = hh; PAl[e*360 + 288 + h] = ll;
    }
    __syncthreads();

    {
        float4v acc[2] = {{0,0,0,0},{0,0,0,0}};
        kloop<11, 2, 360>(PAh, PAl, p1h, p1l, acc, lane, wave);
        const int q = lane >> 4;
        #pragma unroll
        for (int i = 0; i < 2; ++i) {
            const int n = (wave * 2 + i) * 16 + (lane & 15);
            const float bias = m1_wsb[n];
            #pragma unroll
            for (int r = 0; r < 4; ++r) {
                const int m = q * 4 + r;
                const float x = fmaxf(acc[i][r] + bias, 0.f);
                unsigned short h, l; split_bf(x, h, l);
                PBh[m*168 + n] = h; PBl[m*168 + n] = l;
            }
        }
    }
    for (int g = tid; g < 16 * 16; g += 256) {
        const int e = g & 15, o = g >> 4;
        float a0 = 0.f, a1 = 0.f, a2 = 0.f;
        for (int h = 0; h < 33; ++h) {
            const float w = m1_wv[o*33 + h];
            a0 = fmaf(B1[e*101+h*3+0], w, a0);
            a1 = fmaf(B1[e*101+h*3+1], w, a1);
            a2 = fmaf(B1[e*101+h*3+2], w, a2);
        }
        const float nrm = sqrtf(fmaxf(a0*a0 + a1*a1 + a2*a2, EPSF));
        const float sg = 1.f / (1.f + __expf(-nrm));
        B2[e*51+o*3+0] = a0*sg; B2[e*51+o*3+1] = a1*sg; B2[e*51+o*3+2] = a2*sg;
    }
    __syncthreads();

    for (int g = tid; g < 16 * 48; g += 256) {
        const int e = g & 15, r = g >> 4, t = r % 3, h = r / 3;
        float a = 0.f;
        for (int c = 0; c < 16; ++c) a = fmaf(B2[e*51 + c*3 + t], m2_wh[h*16 + c], a);
        B1[e*101 + h*3 + t] = a;
    }
    __syncthreads();
    for (int g = tid; g < 16 * 16; g += 256) {
        const int e = g & 15, h = g >> 4;
        const float a = B1[e*101+h*3], b = B1[e*101+h*3+1], c = B1[e*101+h*3+2];
        const float vn = sqrtf(fmaxf(a*a + b*b + c*c, EPSF));
        unsigned short hh, ll; split_bf(vn, hh, ll);
        PBh[e*168 + 128 + h] = hh; PBl[e*168 + 128 + h] = ll;
        PBh[e*168 + 144 + h] = 0;  PBl[e*168 + 144 + h] = 0;
    }
    __syncthreads();

    {
        float4v acc[2] = {{0,0,0,0},{0,0,0,0}};
        kloop<5, 2, 168>(PBh, PBl, p2h, p2l, acc, lane, wave);
        const int q = lane >> 4;
        #pragma unroll
        for (int i = 0; i < 2; ++i) {
            const int n = (wave * 2 + i) * 16 + (lane & 15);
            const float bias = m2_wsb[n];
            #pragma unroll
            for (int r = 0; r < 4; ++r) {
                const int m = q * 4 + r;
                const float x = fmaxf(acc[i][r] + bias, 0.f);
                unsigned short h, l; split_bf(x, h, l);
                PAh[m*360 + n] = h; PAl[m*360 + n] = l;
            }
        }
    }
    for (int g = tid; g < 16 * 16; g += 256) {
        const int e = g & 15, o = g >> 4;
        float a0 = 0.f, a1 = 0.f, a2 = 0.f;
        for (int h = 0; h < 16; ++h) {
            const float w = m2_wv[o*16 + h];
            a0 = fmaf(B1[e*101+h*3+0], w, a0);
            a1 = fmaf(B1[e*101+h*3+1], w, a1);
            a2 = fmaf(B1[e*101+h*3+2], w, a2);
        }
        const float nrm = sqrtf(fmaxf(a0*a0 + a1*a1 + a2*a2, EPSF));
        const float sg = 1.f / (1.f + __expf(-nrm));
        B2[e*51+o*3+0] = a0*sg; B2[e*51+o*3+1] = a1*sg; B2[e*51+o*3+2] = a2*sg;
    }
    __syncthreads();

    for (int g = tid; g < 16 * 48; g += 256) {
        const int e = g & 15, r = g >> 4, t = r % 3, h = r / 3;
        float a = 0.f;
        for (int c = 0; c < 16; ++c) a = fmaf(B2[e*51 + c*3 + t], m3_wh[h*16 + c], a);
        B1[e*101 + h*3 + t] = a;
    }
    __syncthreads();
    for (int g = tid; g < 16 * 16; g += 256) {
        const int e = g & 15, h = g >> 4;
        const float a = B1[e*101+h*3], b = B1[e*101+h*3+1], c = B1[e*101+h*3+2];
        const float vn = sqrtf(fmaxf(a*a + b*b + c*c, EPSF));
        unsigned short hh, ll; split_bf(vn, hh, ll);
        PAh[e*360 + 128 + h] = hh; PAl[e*360 + 128 + h] = ll;
        PAh[e*360 + 144 + h] = 0;  PAl[e*360 + 144 + h] = 0;
    }
    __syncthreads();

    float4v acc3[2] = {{0,0,0,0},{0,0,0,0}};
    kloop<5, 2, 360>(PAh, PAl, p3h, p3l, acc3, lane, wave);
    for (int g = tid; g < 16 * 16; g += 256) {
        const int e = g & 15, o = g >> 4;
        float a0 = 0.f, a1 = 0.f, a2 = 0.f;
        for (int h = 0; h < 16; ++h) {
            const float w = m3_wv[o*16 + h];
            a0 = fmaf(B1[e*101+h*3+0], w, a0);
            a1 = fmaf(B1[e*101+h*3+1], w, a1);
            a2 = fmaf(B1[e*101+h*3+2], w, a2);
        }
        B2[e*51+o*3+0] = a0; B2[e*51+o*3+1] = a1; B2[e*51+o*3+2] = a2;
    }
    __syncthreads();

    {
        const int q = lane >> 4;
        #pragma unroll
        for (int i = 0; i < 2; ++i) {
            const int n = (wave * 2 + i) * 16 + (lane & 15);
            const float bias = m3_wsb[n];
            #pragma unroll
            for (int r = 0; r < 4; ++r) {
                const int m = q * 4 + r;
                const int d = sdst[m];
                if (d >= 0) atomicAdd(&agg_s[(size_t)d * 128 + n], acc3[i][r] + bias);
            }
        }
    }
    for (int g = tid; g < 16 * 48; g += 256) {
        const int e = g / 48, j = g % 48;
        const int d = sdst[e];
        if (d >= 0) atomicAdd(&agg_v[(size_t)d * 48 + j], B2[e*51 + j]);
    }
    if (tid < 16 && sdst[tid] >= 0) atomicAdd(&cnt[sdst[tid]], 1.0f);
}

// ===========================================================================
// R3's proven fp32-VALU node path (verbatim port)
// ===========================================================================
template<int VI, int H, int SIcat, int KP, int SO, int VO, bool ACT,
         int SSTR, int VSTR, int HSTR, int SOSTR, int VOSTR>
__device__ __forceinline__ void gvp4(
    float* S, const float* V, float* VH, float* SOb, float* VOb,
    const float* __restrict__ wh, const float* __restrict__ wswP,
    const float* __restrict__ wsb, const float* __restrict__ wv, int lane)
{
    static_assert(SO % 64 == 0 && KP % 4 == 0, "shape");
    for (int idx = lane; idx < H * 3; idx += 64) {
        const int h = idx / 3, t = idx - h * 3;
        const float* w = wh + h * VI;
        float acc[ED] = {0.f, 0.f, 0.f, 0.f};
        for (int c = 0; c < VI; ++c) {
            const float wc = w[c];
            #pragma unroll
            for (int e = 0; e < ED; ++e) acc[e] = fmaf(V[e * VSTR + c * 3 + t], wc, acc[e]);
        }
        #pragma unroll
        for (int e = 0; e < ED; ++e) VH[e * HSTR + idx] = acc[e];
    }
    __syncthreads();
    for (int h = lane; h < H; h += 64) {
        #pragma unroll
        for (int e = 0; e < ED; ++e) {
            const float a = VH[e * HSTR + h * 3 + 0], b = VH[e * HSTR + h * 3 + 1],
                        c = VH[e * HSTR + h * 3 + 2];
            S[e * SSTR + SIcat + h] = sqrtf(fmaxf(a * a + b * b + c * c, EPSF));
        }
    }
    __syncthreads();
    constexpr int OF = SO / 64;
    {
        float acc[OF][ED];
        #pragma unroll
        for (int of = 0; of < OF; ++of) {
            const float bias = wsb[lane + of * 64];
            #pragma unroll
            for (int e = 0; e < ED; ++e) acc[of][e] = bias;
        }
        for (int k = 0; k < KP; k += 4) {
            float4 sv[ED];
            #pragma unroll
            for (int e = 0; e < ED; ++e) sv[e] = *(const float4*)&S[e * SSTR + k];
            #pragma unroll
            for (int of = 0; of < OF; ++of) {
                const float4 w = *(const float4*)&wswP[(size_t)(lane + of * 64) * KP + k];
                #pragma unroll
                for (int e = 0; e < ED; ++e) {
                    acc[of][e] = fmaf(w.x, sv[e].x, acc[of][e]);
                    acc[of][e] = fmaf(w.y, sv[e].y, acc[of][e]);
                    acc[of][e] = fmaf(w.z, sv[e].z, acc[of][e]);
                    acc[of][e] = fmaf(w.w, sv[e].w, acc[of][e]);
                }
            }
        }
        #pragma unroll
        for (int of = 0; of < OF; ++of)
            #pragma unroll
            for (int e = 0; e < ED; ++e) {
                float a = acc[of][e];
                if (ACT) a = fmaxf(a, 0.f);
                SOb[e * SOSTR + lane + of * 64] = a;
            }
    }
    for (int idx = lane; idx < VO * 3; idx += 64) {
        const int o = idx / 3, t = idx - o * 3;
        const float* w = wv + o * H;
        float acc[ED] = {0.f, 0.f, 0.f, 0.f};
        for (int h = 0; h < H; ++h) {
            const float wc = w[h];
            #pragma unroll
            for (int e = 0; e < ED; ++e) acc[e] = fmaf(VH[e * HSTR + h * 3 + t], wc, acc[e]);
        }
        #pragma unroll
        for (int e = 0; e < ED; ++e) VOb[e * VOSTR + idx] = acc[e];
    }
    __syncthreads();
    if (ACT) {
        for (int o = lane; o < VO; o += 64) {
            #pragma unroll
            for (int e = 0; e < ED; ++e) {
                float* p = VOb + e * VOSTR + o * 3;
                const float a = p[0], b = p[1], c = p[2];
                const float nrm = sqrtf(fmaxf(a * a + b * b + c * c, EPSF));
                const float sg = 1.f / (1.f + __expf(-nrm));
                p[0] = a * sg; p[1] = b * sg; p[2] = c * sg;
            }
        }
        __syncthreads();
    }
}

template<int SSTR, int VSTR>
__device__ __forceinline__ void layer_norm4(float* S, float* V,
    const float* __restrict__ g, const float* __restrict__ b, float* red, int lane)
{
    #pragma unroll
    for (int e = 0; e < ED; ++e) {
        float x0 = S[e * SSTR + lane], x1 = S[e * SSTR + 64 + lane];
        float sum = x0 + x1;
        #pragma unroll
        for (int off = 32; off > 0; off >>= 1) sum += __shfl_xor(sum, off, 64);
        const float mu = sum * (1.f / 128.f);
        const float d0 = x0 - mu, d1 = x1 - mu;
        float vs = d0 * d0 + d1 * d1;
        #pragma unroll
        for (int off = 32; off > 0; off >>= 1) vs += __shfl_xor(vs, off, 64);
        const float rstd = rsqrtf(vs * (1.f / 128.f) + 1e-5f);
        S[e * SSTR + lane]      = d0 * rstd * g[lane]      + b[lane];
        S[e * SSTR + 64 + lane] = d1 * rstd * g[lane + 64] + b[lane + 64];

        if (lane < 16) {
            const float a = V[e * VSTR + lane * 3], bb = V[e * VSTR + lane * 3 + 1],
                        cc = V[e * VSTR + lane * 3 + 2];
            const float vn = fmaxf(a * a + bb * bb + cc * cc, EPSF);
            red[lane]      = vn;
            red[16 + lane] = (vn > 2.f * EPSF) ? 1.f : 0.f;
        }
        __syncthreads();
        float sn = 0.f, sm = 0.f;
        #pragma unroll
        for (int i = 0; i < 16; ++i) { sn += red[i] * red[16 + i]; sm += red[16 + i]; }
        const float rvm = rsqrtf(sn / (EPSF + sm) + EPSF);
        if (lane < 48) V[e * VSTR + lane] = red[16 + lane / 3] * V[e * VSTR + lane] * rvm;
        __syncthreads();
    }
}

__global__ __launch_bounds__(128)
void node_kernel(const float* __restrict__ s, const float* __restrict__ v,
                 const float* __restrict__ f1_wh, const float* __restrict__ f1_wsw,
                 const float* __restrict__ f1_wsb, const float* __restrict__ f1_wv,
                 const float* __restrict__ f2_wh, const float* __restrict__ f2_wsw,
                 const float* __restrict__ f2_wsb, const float* __restrict__ f2_wv,
                 const float* __restrict__ ln0_g, const float* __restrict__ ln0_b,
                 const float* __restrict__ ln1_g, const float* __restrict__ ln1_b,
                 const float* __restrict__ agg_s, const float* __restrict__ agg_v,
                 const float* __restrict__ cnt,
                 float* __restrict__ out, int N)
{
    __shared__ __align__(16) float nsm[2 * 4608];
    const int wave = threadIdx.x >> 6, lane = threadIdx.x & 63;
    float* S1  = nsm + wave * 4608;
    float* V1  = S1 + 640;
    float* FS  = S1 + 832;
    float* FV  = S1 + 3008;
    float* VHb = S1 + 3392;
    float* OS  = S1 + 3776;
    float* OV  = S1 + 4288;
    float* red = S1 + 4480;

    const int n0 = (blockIdx.x * 2 + wave) * ED;
    bool oks[ED];
    #pragma unroll
    for (int e = 0; e < ED; ++e) {
        const int ng = n0 + e;
        oks[e] = (ng < N);
        const int n = oks[e] ? ng : (N - 1);
        const float inv = 1.f / fmaxf(cnt[n], 1.f);
        if (lane < 32) {
            const float4 a = ((const float4*)(s + (size_t)n * 128))[lane];
            const float4 b = ((const float4*)(agg_s + (size_t)n * 128))[lane];
            float4 r; r.x = a.x + b.x * inv; r.y = a.y + b.y * inv;
            r.z = a.z + b.z * inv; r.w = a.w + b.w * inv;
            ((float4*)(S1 + e * 160))[lane] = r;
        }
        if (lane < 12) {
            const float4 a = ((const float4*)(v + (size_t)n * 48))[lane];
            const float4 b = ((const float4*)(agg_v + (size_t)n * 48))[lane];
            float4 r; r.x = a.x + b.x * inv; r.y = a.y + b.y * inv;
            r.z = a.z + b.z * inv; r.w = a.w + b.w * inv;
            ((float4*)(V1 + e * 48))[lane] = r;
        }
    }
    __syncthreads();

    layer_norm4<160, 48>(S1, V1, ln0_g, ln0_b, red, lane);

    gvp4<16, 32, 128, 160, 512, 32, true, 160, 48, 96, 544, 96>(
        S1, V1, VHb, FS, FV, f1_wh, f1_wsw, f1_wsb, f1_wv, lane);
    gvp4<32, 32, 512, 544, 128, 16, false, 544, 96, 96, 128, 48>(
        FS, FV, VHb, OS, OV, f2_wh, f2_wsw, f2_wsb, f2_wv, lane);

    #pragma unroll
    for (int e = 0; e < ED; ++e) {
        for (int i = lane; i < 128; i += 64) OS[e * 128 + i] += S1[e * 160 + i];
        if (lane < 48) OV[e * 48 + lane] += V1[e * 48 + lane];
    }
    __syncthreads();

    layer_norm4<128, 48>(OS, OV, ln1_g, ln1_b, red, lane);

    #pragma unroll
    for (int e = 0; e < ED; ++e) {
        if (!oks[e]) continue;
        const int n = n0 + e;
        if (lane < 32)
            ((float4*)(out + (size_t)n * 128))[lane] = ((const float4*)(OS + e * 128))[lane];
        if (lane < 12)
            ((float4*)(out + (size_t)N * 128 + (size_t)n * 48))[lane] =
                ((const float4*)(OV + e * 48))[lane];
    }
}

// ---------------------------------------------------------------------------
extern "C" void kernel_launch(void* const* d_in, const int* in_sizes, int n_in,
                              void* d_out, int out_size, void* d_ws, size_t ws_size,
                              hipStream_t stream)
{
    const float* s    = (const float*)d_in[0];
    const float* v    = (const float*)d_in[1];
    const int*   eidx = (const int*)d_in[2];
    const float* es   = (const float*)d_in[3];
    const float* ev   = (const float*)d_in[4];
    const float* m1_wh = (const float*)d_in[5];
    const float* m1_wsw = (const float*)d_in[6];
    const float* m1_wsb = (const float*)d_in[7];
    const float* m1_wv = (const float*)d_in[8];
    const float* m2_wh = (const float*)d_in[9];
    const float* m2_wsw = (const float*)d_in[10];
    const float* m2_wsb = (const float*)d_in[11];
    const float* m2_wv = (const float*)d_in[12];
    const float* m3_wh = (const float*)d_in[13];
    const float* m3_wsw = (const float*)d_in[14];
    const float* m3_wsb = (const float*)d_in[15];
    const float* m3_wv = (const float*)d_in[16];
    const float* f1_wh = (const float*)d_in[17];
    const float* f1_wsw = (const float*)d_in[18];
    const float* f1_wsb = (const float*)d_in[19];
    const float* f1_wv = (const float*)d_in[20];
    const float* f2_wh = (const float*)d_in[21];
    const float* f2_wsw = (const float*)d_in[22];
    const float* f2_wsb = (const float*)d_in[23];
    const float* f2_wv = (const float*)d_in[24];
    const float* ln0_g = (const float*)d_in[25];
    const float* ln0_b = (const float*)d_in[26];
    const float* ln1_g = (const float*)d_in[27];
    const float* ln1_b = (const float*)d_in[28];

    const int N = in_sizes[0] / 128;
    const int E = in_sizes[2] / 2;

    float* agg_s = (float*)d_ws;                       // N*128 f32
    float* agg_v = agg_s + (size_t)N * 128;            // N*48  f32
    float* cnt   = agg_v + (size_t)N * 48;             // N     f32
    unsigned short* pk = (unsigned short*)(cnt + N);
    const int S_M1 = 45056, S_M23 = 20480;
    unsigned short* p1h = pk;            unsigned short* p1l = p1h + S_M1;
    unsigned short* p2h = p1l + S_M1;    unsigned short* p2l = p2h + S_M23;
    unsigned short* p3h = p2l + S_M23;   unsigned short* p3l = p3h + S_M23;

    hipMemsetAsync(d_ws, 0, (size_t)N * 177 * sizeof(float), stream);

    pack_w<<<dim3((S_M1  + 255) / 256), dim3(256), 0, stream>>>(m1_wsw, p1h, p1l, 128, 321, 11);
    pack_w<<<dim3((S_M23 + 255) / 256), dim3(256), 0, stream>>>(m2_wsw, p2h, p2l, 128, 144, 5);
    pack_w<<<dim3((S_M23 + 255) / 256), dim3(256), 0, stream>>>(m3_wsw, p3h, p3l, 128, 144, 5);

    edge_kernel<<<dim3((E + 15) / 16), dim3(256), 0, stream>>>(
        s, v, eidx, es, ev,
        m1_wh, m1_wsb, m1_wv,
        m2_wh, m2_wsb, m2_wv,
        m3_wh, m3_wsb, m3_wv,
        p1h, p1l, p2h, p2l, p3h, p3l,
        agg_s, agg_v, cnt, E);

    node_kernel<<<dim3((N + 7) / 8), dim3(128), 0, stream>>>(
        s, v,
        f1_wh, f1_wsw, f1_wsb, f1_wv,
        f2_wh, f2_wsw, f2_wsb, f2_wv,
        ln0_g, ln0_b, ln1_g, ln1_b,
        agg_s, agg_v, cnt,
        (float*)d_out, N);
}

// Round 6
// 1916.244 us; speedup vs baseline: 8.6724x; 1.0668x over previous
//
#include <hip/hip_runtime.h>

#define EPSF 1e-8f
constexpr int ED = 4;   // nodes per wave in node kernel

typedef __attribute__((ext_vector_type(8))) short short8;
typedef __attribute__((ext_vector_type(4))) float float4v;

// ---- fp32 -> bf16 hi/lo split (RNE) ---------------------------------------
__device__ __forceinline__ unsigned bfhi_bits(float x) {
    unsigned u = __float_as_uint(x);
    return (u + 0x7fffu + ((u >> 16) & 1u)) >> 16;
}
__device__ __forceinline__ float bits2f(unsigned b) { return __uint_as_float(b << 16); }
__device__ __forceinline__ void split_bf(float x, unsigned short& h, unsigned short& l) {
    unsigned hb = bfhi_bits(x);
    h = (unsigned short)hb;
    l = (unsigned short)bfhi_bits(x - bits2f(hb));
}

// ---------------------------------------------------------------------------
// Pack W[NO][K] fp32 (row-major) into MFMA B-fragment order, bf16 hi/lo.
// ---------------------------------------------------------------------------
__global__ void pack_w(const float* __restrict__ W, unsigned short* __restrict__ hi,
                       unsigned short* __restrict__ lo, int NO, int K, int steps) {
    const int gid = blockIdx.x * 256 + threadIdx.x;
    const int total = (NO >> 4) * steps * 512;
    if (gid >= total) return;
    const int j = gid & 7, l = (gid >> 3) & 63, rest = gid >> 9;
    const int t = rest % steps, nt = rest / steps;
    const int n = nt * 16 + (l & 15);
    const int k = t * 32 + ((l >> 4) << 3) + j;
    const float x = (k < K) ? W[(size_t)n * K + k] : 0.f;
    unsigned short h, lw;
    split_bf(x, h, lw);
    hi[gid] = h; lo[gid] = lw;
}

// ---------------------------------------------------------------------------
// 3-pass split-bf16 MFMA K-loop (validated R4/R5).
// ---------------------------------------------------------------------------
template<int STEPS, int NTPW, int ASTR>
__device__ __forceinline__ void kloop(const unsigned short* PAh, const unsigned short* PAl,
    const unsigned short* __restrict__ wph, const unsigned short* __restrict__ wpl,
    float4v* acc, int lane, int wave)
{
    const int m = lane & 15, q = lane >> 4;
    for (int t = 0; t < STEPS; ++t) {
        const int k0 = t * 32 + q * 8;
        const short8 ah = *(const short8*)(PAh + m * ASTR + k0);
        const short8 al = *(const short8*)(PAl + m * ASTR + k0);
        #pragma unroll
        for (int i = 0; i < NTPW; ++i) {
            const int nt = wave * NTPW + i;
            const size_t off = ((size_t)(nt * STEPS + t) * 64 + lane) * 8;
            const short8 bh = *(const short8*)(wph + off);
            const short8 bl = *(const short8*)(wpl + off);
            acc[i] = __builtin_amdgcn_mfma_f32_16x16x32_bf16(ah, bh, acc[i], 0, 0, 0);
            acc[i] = __builtin_amdgcn_mfma_f32_16x16x32_bf16(al, bh, acc[i], 0, 0, 0);
            acc[i] = __builtin_amdgcn_mfma_f32_16x16x32_bf16(ah, bl, acc[i], 0, 0, 0);
        }
    }
}

// ---------------------------------------------------------------------------
// Edge kernel: 16 edges / block, 256 threads (4 waves).
// Strides: PA 352 shorts, PB 160 shorts, B0/B1 100 floats, B2 52 floats.
// B0 (fp32 V-concat) aliases the PB region (disjoint live ranges).
// Thread map for elementwise phases: e = tid&15, q16 = tid>>4  (pow2, no div).
// ---------------------------------------------------------------------------
constexpr int SA  = 352;
constexpr int SBs = 160;
constexpr int SB1 = 100;
constexpr int SB2 = 52;

__global__ __launch_bounds__(256)
void edge_kernel(const float* __restrict__ s, const float* __restrict__ v,
                 const int* __restrict__ eidx,
                 const float* __restrict__ es, const float* __restrict__ ev,
                 const float* __restrict__ m1_wh, const float* __restrict__ m1_wsb,
                 const float* __restrict__ m1_wv,
                 const float* __restrict__ m2_wh, const float* __restrict__ m2_wsb,
                 const float* __restrict__ m2_wv,
                 const float* __restrict__ m3_wh, const float* __restrict__ m3_wsb,
                 const float* __restrict__ m3_wv,
                 const unsigned short* __restrict__ p1h, const unsigned short* __restrict__ p1l,
                 const unsigned short* __restrict__ p2h, const unsigned short* __restrict__ p2l,
                 const unsigned short* __restrict__ p3h, const unsigned short* __restrict__ p3l,
                 float* __restrict__ agg_s, float* __restrict__ agg_v,
                 float* __restrict__ cnt, int E)
{
    __shared__ __align__(16) unsigned short PAh[16 * SA], PAl[16 * SA];
    __shared__ __align__(16) unsigned short PBmem[2 * 16 * SBs];
    __shared__ __align__(16) float B1[16 * SB1];
    __shared__ __align__(16) float B2[16 * SB2];
    __shared__ int ssrc[16], sgd[16], sdst[16], seid[16];

    unsigned short* PBh = PBmem;
    unsigned short* PBl = PBmem + 16 * SBs;
    float* B0 = (float*)PBmem;          // aliases PB: dead before PB is written

    const int tid = threadIdx.x, lane = tid & 63, wave = tid >> 6;
    const int e = tid & 15, q16 = tid >> 4;
    const int e0 = blockIdx.x * 16;

    // E1: indices
    if (tid < 16) {
        const int eg = e0 + tid;
        const bool ok = (eg < E);
        const int ee = ok ? eg : (E - 1);
        seid[tid] = ee;
        ssrc[tid] = eidx[ee];
        const int d = eidx[E + ee];
        sgd[tid] = d;
        sdst[tid] = ok ? d : -1;
    }
    __syncthreads();

    // E2a: S-concat gather -> PA[0,288) as short8 b128 writes (8 floats/task)
    #pragma unroll
    for (int it = 0; it < 3; ++it) {
        const int c = q16 + 16 * it;
        if (c < 36) {
            const float* srcp; int col;
            if (c < 16)      { srcp = s  + (size_t)ssrc[e] * 128 + 8 * c;       col = 8 * c; }
            else if (c < 20) { srcp = es + (size_t)seid[e] * 32 + 8 * (c - 16); col = 128 + 8 * (c - 16); }
            else             { srcp = s  + (size_t)sgd[e]  * 128 + 8 * (c - 20); col = 160 + 8 * (c - 20); }
            const float4 x = ((const float4*)srcp)[0];
            const float4 y = ((const float4*)srcp)[1];
            short8 hv, lv; unsigned short h, l;
            split_bf(x.x, h, l); hv[0] = h; lv[0] = l;
            split_bf(x.y, h, l); hv[1] = h; lv[1] = l;
            split_bf(x.z, h, l); hv[2] = h; lv[2] = l;
            split_bf(x.w, h, l); hv[3] = h; lv[3] = l;
            split_bf(y.x, h, l); hv[4] = h; lv[4] = l;
            split_bf(y.y, h, l); hv[5] = h; lv[5] = l;
            split_bf(y.z, h, l); hv[6] = h; lv[6] = l;
            split_bf(y.w, h, l); hv[7] = h; lv[7] = l;
            *(short8*)(PAh + e * SA + col) = hv;
            *(short8*)(PAl + e * SA + col) = lv;
        }
    }
    // zero-pad PA cols [320,352)
    #pragma unroll
    for (int it = 0; it < 2; ++it) {
        const int col = 320 + q16 + 16 * it;
        PAh[e * SA + col] = 0; PAl[e * SA + col] = 0;
    }
    // E2b: V-concat gather -> B0 (fp32, cols c*3+t, 99 used)
    {
        if (q16 < 12) {
            const float4 x = ((const float4*)(v + (size_t)ssrc[e] * 48))[q16];
            *(float4*)(B0 + e * SB1 + 4 * q16) = x;
        } else if (q16 == 12) {
            const float* qv = ev + (size_t)seid[e] * 3;
            float* p = B0 + e * SB1 + 48;
            p[0] = qv[0]; p[1] = qv[1]; p[2] = qv[2];
        }
        if (q16 < 12) {
            const float4 x = ((const float4*)(v + (size_t)sgd[e] * 48))[q16];
            float* p = B0 + e * SB1 + 51 + 4 * q16;
            p[0] = x.x; p[1] = x.y; p[2] = x.z; p[3] = x.w;
        }
    }
    __syncthreads();

    // E3+E4 fused: vh1 = m1_wh @ Vcat -> B1; vn1 -> PA[288,321)
    #pragma unroll
    for (int it = 0; it < 3; ++it) {
        const int h = q16 + 16 * it;
        if (h < 33) {
            const float* wrow = m1_wh + h * 33;
            const float* vb = B0 + e * SB1;
            float a0 = 0.f, a1 = 0.f, a2 = 0.f;
            for (int c = 0; c < 33; ++c) {
                const float w = wrow[c];
                a0 = fmaf(vb[c * 3 + 0], w, a0);
                a1 = fmaf(vb[c * 3 + 1], w, a1);
                a2 = fmaf(vb[c * 3 + 2], w, a2);
            }
            float* o = B1 + e * SB1 + h * 3;
            o[0] = a0; o[1] = a1; o[2] = a2;
            const float vn = sqrtf(fmaxf(a0 * a0 + a1 * a1 + a2 * a2, EPSF));
            unsigned short hh, ll; split_bf(vn, hh, ll);
            PAh[e * SA + 288 + h] = hh; PAl[e * SA + 288 + h] = ll;
        }
    }
    __syncthreads();

    // E5: m1 MFMA (K=352) -> relu -> PB[0,128); vout1 -> B2
    {
        float4v acc[2] = {{0,0,0,0},{0,0,0,0}};
        kloop<11, 2, SA>(PAh, PAl, p1h, p1l, acc, lane, wave);
        const int q = lane >> 4;
        #pragma unroll
        for (int i = 0; i < 2; ++i) {
            const int n = (wave * 2 + i) * 16 + (lane & 15);
            const float bias = m1_wsb[n];
            #pragma unroll
            for (int r = 0; r < 4; ++r) {
                const int m = q * 4 + r;
                const float x = fmaxf(acc[i][r] + bias, 0.f);
                unsigned short h, l; split_bf(x, h, l);
                PBh[m * SBs + n] = h; PBl[m * SBs + n] = l;
            }
        }
    }
    {   // vout1: o = q16 (VO=16), all threads active
        const int o = q16;
        float a0 = 0.f, a1 = 0.f, a2 = 0.f;
        for (int h = 0; h < 33; ++h) {
            const float w = m1_wv[o * 33 + h];
            const float* p = B1 + e * SB1 + h * 3;
            a0 = fmaf(p[0], w, a0); a1 = fmaf(p[1], w, a1); a2 = fmaf(p[2], w, a2);
        }
        const float nrm = sqrtf(fmaxf(a0 * a0 + a1 * a1 + a2 * a2, EPSF));
        const float sg = 1.f / (1.f + __expf(-nrm));
        float* p2 = B2 + e * SB2 + o * 3;
        p2[0] = a0 * sg; p2[1] = a1 * sg; p2[2] = a2 * sg;
    }
    __syncthreads();

    // E6+E7 fused: vh2 -> B1; vn2 -> PB[128,144); zero PB[144,160)
    {
        const int h = q16;
        float a0 = 0.f, a1 = 0.f, a2 = 0.f;
        for (int c = 0; c < 16; ++c) {
            const float w = m2_wh[h * 16 + c];
            const float* p = B2 + e * SB2 + c * 3;
            a0 = fmaf(p[0], w, a0); a1 = fmaf(p[1], w, a1); a2 = fmaf(p[2], w, a2);
        }
        float* o = B1 + e * SB1 + h * 3;
        o[0] = a0; o[1] = a1; o[2] = a2;
        const float vn = sqrtf(fmaxf(a0 * a0 + a1 * a1 + a2 * a2, EPSF));
        unsigned short hh, ll; split_bf(vn, hh, ll);
        PBh[e * SBs + 128 + h] = hh; PBl[e * SBs + 128 + h] = ll;
        PBh[e * SBs + 144 + h] = 0;  PBl[e * SBs + 144 + h] = 0;
    }
    __syncthreads();

    // E8: m2 MFMA (K=160) -> relu -> PA[0,128); vout2 -> B2
    {
        float4v acc[2] = {{0,0,0,0},{0,0,0,0}};
        kloop<5, 2, SBs>(PBh, PBl, p2h, p2l, acc, lane, wave);
        const int q = lane >> 4;
        #pragma unroll
        for (int i = 0; i < 2; ++i) {
            const int n = (wave * 2 + i) * 16 + (lane & 15);
            const float bias = m2_wsb[n];
            #pragma unroll
            for (int r = 0; r < 4; ++r) {
                const int m = q * 4 + r;
                const float x = fmaxf(acc[i][r] + bias, 0.f);
                unsigned short h, l; split_bf(x, h, l);
                PAh[m * SA + n] = h; PAl[m * SA + n] = l;
            }
        }
    }
    {   // vout2
        const int o = q16;
        float a0 = 0.f, a1 = 0.f, a2 = 0.f;
        for (int h = 0; h < 16; ++h) {
            const float w = m2_wv[o * 16 + h];
            const float* p = B1 + e * SB1 + h * 3;
            a0 = fmaf(p[0], w, a0); a1 = fmaf(p[1], w, a1); a2 = fmaf(p[2], w, a2);
        }
        const float nrm = sqrtf(fmaxf(a0 * a0 + a1 * a1 + a2 * a2, EPSF));
        const float sg = 1.f / (1.f + __expf(-nrm));
        float* p2 = B2 + e * SB2 + o * 3;
        p2[0] = a0 * sg; p2[1] = a1 * sg; p2[2] = a2 * sg;
    }
    __syncthreads();

    // E9+E10 fused: vh3 -> B1; vn3 -> PA[128,144); zero PA[144,160)
    {
        const int h = q16;
        float a0 = 0.f, a1 = 0.f, a2 = 0.f;
        for (int c = 0; c < 16; ++c) {
            const float w = m3_wh[h * 16 + c];
            const float* p = B2 + e * SB2 + c * 3;
            a0 = fmaf(p[0], w, a0); a1 = fmaf(p[1], w, a1); a2 = fmaf(p[2], w, a2);
        }
        float* o = B1 + e * SB1 + h * 3;
        o[0] = a0; o[1] = a1; o[2] = a2;
        const float vn = sqrtf(fmaxf(a0 * a0 + a1 * a1 + a2 * a2, EPSF));
        unsigned short hh, ll; split_bf(vn, hh, ll);
        PAh[e * SA + 128 + h] = hh; PAl[e * SA + 128 + h] = ll;
        PAh[e * SA + 144 + h] = 0;  PAl[e * SA + 144 + h] = 0;
    }
    __syncthreads();

    // E11: m3 MFMA (K=160, no act) + vout3 (no act) -> B2
    float4v acc3[2] = {{0,0,0,0},{0,0,0,0}};
    kloop<5, 2, SA>(PAh, PAl, p3h, p3l, acc3, lane, wave);
    {
        const int o = q16;
        float a0 = 0.f, a1 = 0.f, a2 = 0.f;
        for (int h = 0; h < 16; ++h) {
            const float w = m3_wv[o * 16 + h];
            const float* p = B1 + e * SB1 + h * 3;
            a0 = fmaf(p[0], w, a0); a1 = fmaf(p[1], w, a1); a2 = fmaf(p[2], w, a2);
        }
        float* p2 = B2 + e * SB2 + o * 3;
        p2[0] = a0; p2[1] = a1; p2[2] = a2;
    }
    __syncthreads();

    // E12: scatter-add
    {
        const int q = lane >> 4;
        #pragma unroll
        for (int i = 0; i < 2; ++i) {
            const int n = (wave * 2 + i) * 16 + (lane & 15);
            const float bias = m3_wsb[n];
            #pragma unroll
            for (int r = 0; r < 4; ++r) {
                const int m = q * 4 + r;
                const int d = sdst[m];
                if (d >= 0) atomicAdd(&agg_s[(size_t)d * 128 + n], acc3[i][r] + bias);
            }
        }
    }
    #pragma unroll
    for (int it = 0; it < 3; ++it) {
        const int j = q16 + 16 * it;     // j < 48 exactly
        const int d = sdst[e];
        if (d >= 0) atomicAdd(&agg_v[(size_t)d * 48 + j], B2[e * SB2 + j]);
    }
    if (tid < 16 && sdst[tid] >= 0) atomicAdd(&cnt[sdst[tid]], 1.0f);
}

// ===========================================================================
// R3/R5's proven fp32-VALU node path (verbatim)
// ===========================================================================
template<int VI, int H, int SIcat, int KP, int SO, int VO, bool ACT,
         int SSTR, int VSTR, int HSTR, int SOSTR, int VOSTR>
__device__ __forceinline__ void gvp4(
    float* S, const float* V, float* VH, float* SOb, float* VOb,
    const float* __restrict__ wh, const float* __restrict__ wswP,
    const float* __restrict__ wsb, const float* __restrict__ wv, int lane)
{
    static_assert(SO % 64 == 0 && KP % 4 == 0, "shape");
    for (int idx = lane; idx < H * 3; idx += 64) {
        const int h = idx / 3, t = idx - h * 3;
        const float* w = wh + h * VI;
        float acc[ED] = {0.f, 0.f, 0.f, 0.f};
        for (int c = 0; c < VI; ++c) {
            const float wc = w[c];
            #pragma unroll
            for (int e = 0; e < ED; ++e) acc[e] = fmaf(V[e * VSTR + c * 3 + t], wc, acc[e]);
        }
        #pragma unroll
        for (int e = 0; e < ED; ++e) VH[e * HSTR + idx] = acc[e];
    }
    __syncthreads();
    for (int h = lane; h < H; h += 64) {
        #pragma unroll
        for (int e = 0; e < ED; ++e) {
            const float a = VH[e * HSTR + h * 3 + 0], b = VH[e * HSTR + h * 3 + 1],
                        c = VH[e * HSTR + h * 3 + 2];
            S[e * SSTR + SIcat + h] = sqrtf(fmaxf(a * a + b * b + c * c, EPSF));
        }
    }
    __syncthreads();
    constexpr int OF = SO / 64;
    {
        float acc[OF][ED];
        #pragma unroll
        for (int of = 0; of < OF; ++of) {
            const float bias = wsb[lane + of * 64];
            #pragma unroll
            for (int e = 0; e < ED; ++e) acc[of][e] = bias;
        }
        for (int k = 0; k < KP; k += 4) {
            float4 sv[ED];
            #pragma unroll
            for (int e = 0; e < ED; ++e) sv[e] = *(const float4*)&S[e * SSTR + k];
            #pragma unroll
            for (int of = 0; of < OF; ++of) {
                const float4 w = *(const float4*)&wswP[(size_t)(lane + of * 64) * KP + k];
                #pragma unroll
                for (int e = 0; e < ED; ++e) {
                    acc[of][e] = fmaf(w.x, sv[e].x, acc[of][e]);
                    acc[of][e] = fmaf(w.y, sv[e].y, acc[of][e]);
                    acc[of][e] = fmaf(w.z, sv[e].z, acc[of][e]);
                    acc[of][e] = fmaf(w.w, sv[e].w, acc[of][e]);
                }
            }
        }
        #pragma unroll
        for (int of = 0; of < OF; ++of)
            #pragma unroll
            for (int e = 0; e < ED; ++e) {
                float a = acc[of][e];
                if (ACT) a = fmaxf(a, 0.f);
                SOb[e * SOSTR + lane + of * 64] = a;
            }
    }
    for (int idx = lane; idx < VO * 3; idx += 64) {
        const int o = idx / 3, t = idx - o * 3;
        const float* w = wv + o * H;
        float acc[ED] = {0.f, 0.f, 0.f, 0.f};
        for (int h = 0; h < H; ++h) {
            const float wc = w[h];
            #pragma unroll
            for (int e = 0; e < ED; ++e) acc[e] = fmaf(VH[e * HSTR + h * 3 + t], wc, acc[e]);
        }
        #pragma unroll
        for (int e = 0; e < ED; ++e) VOb[e * VOSTR + idx] = acc[e];
    }
    __syncthreads();
    if (ACT) {
        for (int o = lane; o < VO; o += 64) {
            #pragma unroll
            for (int e = 0; e < ED; ++e) {
                float* p = VOb + e * VOSTR + o * 3;
                const float a = p[0], b = p[1], c = p[2];
                const float nrm = sqrtf(fmaxf(a * a + b * b + c * c, EPSF));
                const float sg = 1.f / (1.f + __expf(-nrm));
                p[0] = a * sg; p[1] = b * sg; p[2] = c * sg;
            }
        }
        __syncthreads();
    }
}

template<int SSTR, int VSTR>
__device__ __forceinline__ void layer_norm4(float* S, float* V,
    const float* __restrict__ g, const float* __restrict__ b, float* red, int lane)
{
    #pragma unroll
    for (int e = 0; e < ED; ++e) {
        float x0 = S[e * SSTR + lane], x1 = S[e * SSTR + 64 + lane];
        float sum = x0 + x1;
        #pragma unroll
        for (int off = 32; off > 0; off >>= 1) sum += __shfl_xor(sum, off, 64);
        const float mu = sum * (1.f / 128.f);
        const float d0 = x0 - mu, d1 = x1 - mu;
        float vs = d0 * d0 + d1 * d1;
        #pragma unroll
        for (int off = 32; off > 0; off >>= 1) vs += __shfl_xor(vs, off, 64);
        const float rstd = rsqrtf(vs * (1.f / 128.f) + 1e-5f);
        S[e * SSTR + lane]      = d0 * rstd * g[lane]      + b[lane];
        S[e * SSTR + 64 + lane] = d1 * rstd * g[lane + 64] + b[lane + 64];

        if (lane < 16) {
            const float a = V[e * VSTR + lane * 3], bb = V[e * VSTR + lane * 3 + 1],
                        cc = V[e * VSTR + lane * 3 + 2];
            const float vn = fmaxf(a * a + bb * bb + cc * cc, EPSF);
            red[lane]      = vn;
            red[16 + lane] = (vn > 2.f * EPSF) ? 1.f : 0.f;
        }
        __syncthreads();
        float sn = 0.f, sm = 0.f;
        #pragma unroll
        for (int i = 0; i < 16; ++i) { sn += red[i] * red[16 + i]; sm += red[16 + i]; }
        const float rvm = rsqrtf(sn / (EPSF + sm) + EPSF);
        if (lane < 48) V[e * VSTR + lane] = red[16 + lane / 3] * V[e * VSTR + lane] * rvm;
        __syncthreads();
    }
}

__global__ __launch_bounds__(128)
void node_kernel(const float* __restrict__ s, const float* __restrict__ v,
                 const float* __restrict__ f1_wh, const float* __restrict__ f1_wsw,
                 const float* __restrict__ f1_wsb, const float* __restrict__ f1_wv,
                 const float* __restrict__ f2_wh, const float* __restrict__ f2_wsw,
                 const float* __restrict__ f2_wsb, const float* __restrict__ f2_wv,
                 const float* __restrict__ ln0_g, const float* __restrict__ ln0_b,
                 const float* __restrict__ ln1_g, const float* __restrict__ ln1_b,
                 const float* __restrict__ agg_s, const float* __restrict__ agg_v,
                 const float* __restrict__ cnt,
                 float* __restrict__ out, int N)
{
    __shared__ __align__(16) float nsm[2 * 4608];
    const int wave = threadIdx.x >> 6, lane = threadIdx.x & 63;
    float* S1  = nsm + wave * 4608;
    float* V1  = S1 + 640;
    float* FS  = S1 + 832;
    float* FV  = S1 + 3008;
    float* VHb = S1 + 3392;
    float* OS  = S1 + 3776;
    float* OV  = S1 + 4288;
    float* red = S1 + 4480;

    const int n0 = (blockIdx.x * 2 + wave) * ED;
    bool oks[ED];
    #pragma unroll
    for (int e = 0; e < ED; ++e) {
        const int ng = n0 + e;
        oks[e] = (ng < N);
        const int n = oks[e] ? ng : (N - 1);
        const float inv = 1.f / fmaxf(cnt[n], 1.f);
        if (lane < 32) {
            const float4 a = ((const float4*)(s + (size_t)n * 128))[lane];
            const float4 b = ((const float4*)(agg_s + (size_t)n * 128))[lane];
            float4 r; r.x = a.x + b.x * inv; r.y = a.y + b.y * inv;
            r.z = a.z + b.z * inv; r.w = a.w + b.w * inv;
            ((float4*)(S1 + e * 160))[lane] = r;
        }
        if (lane < 12) {
            const float4 a = ((const float4*)(v + (size_t)n * 48))[lane];
            const float4 b = ((const float4*)(agg_v + (size_t)n * 48))[lane];
            float4 r; r.x = a.x + b.x * inv; r.y = a.y + b.y * inv;
            r.z = a.z + b.z * inv; r.w = a.w + b.w * inv;
            ((float4*)(V1 + e * 48))[lane] = r;
        }
    }
    __syncthreads();

    layer_norm4<160, 48>(S1, V1, ln0_g, ln0_b, red, lane);

    gvp4<16, 32, 128, 160, 512, 32, true, 160, 48, 96, 544, 96>(
        S1, V1, VHb, FS, FV, f1_wh, f1_wsw, f1_wsb, f1_wv, lane);
    gvp4<32, 32, 512, 544, 128, 16, false, 544, 96, 96, 128, 48>(
        FS, FV, VHb, OS, OV, f2_wh, f2_wsw, f2_wsb, f2_wv, lane);

    #pragma unroll
    for (int e = 0; e < ED; ++e) {
        for (int i = lane; i < 128; i += 64) OS[e * 128 + i] += S1[e * 160 + i];
        if (lane < 48) OV[e * 48 + lane] += V1[e * 48 + lane];
    }
    __syncthreads();

    layer_norm4<128, 48>(OS, OV, ln1_g, ln1_b, red, lane);

    #pragma unroll
    for (int e = 0; e < ED; ++e) {
        if (!oks[e]) continue;
        const int n = n0 + e;
        if (lane < 32)
            ((float4*)(out + (size_t)n * 128))[lane] = ((const float4*)(OS + e * 128))[lane];
        if (lane < 12)
            ((float4*)(out + (size_t)N * 128 + (size_t)n * 48))[lane] =
                ((const float4*)(OV + e * 48))[lane];
    }
}

// ---------------------------------------------------------------------------
extern "C" void kernel_launch(void* const* d_in, const int* in_sizes, int n_in,
                              void* d_out, int out_size, void* d_ws, size_t ws_size,
                              hipStream_t stream)
{
    const float* s    = (const float*)d_in[0];
    const float* v    = (const float*)d_in[1];
    const int*   eidx = (const int*)d_in[2];
    const float* es   = (const float*)d_in[3];
    const float* ev   = (const float*)d_in[4];
    const float* m1_wh = (const float*)d_in[5];
    const float* m1_wsw = (const float*)d_in[6];
    const float* m1_wsb = (const float*)d_in[7];
    const float* m1_wv = (const float*)d_in[8];
    const float* m2_wh = (const float*)d_in[9];
    const float* m2_wsw = (const float*)d_in[10];
    const float* m2_wsb = (const float*)d_in[11];
    const float* m2_wv = (const float*)d_in[12];
    const float* m3_wh = (const float*)d_in[13];
    const float* m3_wsw = (const float*)d_in[14];
    const float* m3_wsb = (const float*)d_in[15];
    const float* m3_wv = (const float*)d_in[16];
    const float* f1_wh = (const float*)d_in[17];
    const float* f1_wsw = (const float*)d_in[18];
    const float* f1_wsb = (const float*)d_in[19];
    const float* f1_wv = (const float*)d_in[20];
    const float* f2_wh = (const float*)d_in[21];
    const float* f2_wsw = (const float*)d_in[22];
    const float* f2_wsb = (const float*)d_in[23];
    const float* f2_wv = (const float*)d_in[24];
    const float* ln0_g = (const float*)d_in[25];
    const float* ln0_b = (const float*)d_in[26];
    const float* ln1_g = (const float*)d_in[27];
    const float* ln1_b = (const float*)d_in[28];

    const int N = in_sizes[0] / 128;
    const int E = in_sizes[2] / 2;

    float* agg_s = (float*)d_ws;                       // N*128 f32
    float* agg_v = agg_s + (size_t)N * 128;            // N*48  f32
    float* cnt   = agg_v + (size_t)N * 48;             // N     f32
    unsigned short* pk = (unsigned short*)(cnt + N);
    const int S_M1 = 45056, S_M23 = 20480;
    unsigned short* p1h = pk;            unsigned short* p1l = p1h + S_M1;
    unsigned short* p2h = p1l + S_M1;    unsigned short* p2l = p2h + S_M23;
    unsigned short* p3h = p2l + S_M23;   unsigned short* p3l = p3h + S_M23;

    hipMemsetAsync(d_ws, 0, (size_t)N * 177 * sizeof(float), stream);

    pack_w<<<dim3((S_M1  + 255) / 256), dim3(256), 0, stream>>>(m1_wsw, p1h, p1l, 128, 321, 11);
    pack_w<<<dim3((S_M23 + 255) / 256), dim3(256), 0, stream>>>(m2_wsw, p2h, p2l, 128, 144, 5);
    pack_w<<<dim3((S_M23 + 255) / 256), dim3(256), 0, stream>>>(m3_wsw, p3h, p3l, 128, 144, 5);

    edge_kernel<<<dim3((E + 15) / 16), dim3(256), 0, stream>>>(
        s, v, eidx, es, ev,
        m1_wh, m1_wsb, m1_wv,
        m2_wh, m2_wsb, m2_wv,
        m3_wh, m3_wsb, m3_wv,
        p1h, p1l, p2h, p2l, p3h, p3l,
        agg_s, agg_v, cnt, E);

    node_kernel<<<dim3((N + 7) / 8), dim3(128), 0, stream>>>(
        s, v,
        f1_wh, f1_wsw, f1_wsb, f1_wv,
        f2_wh, f2_wsw, f2_wsb, f2_wv,
        ln0_g, ln0_b, ln1_g, ln1_b,
        agg_s, agg_v, cnt,
        (float*)d_out, N);
}